// Round 11
// baseline (11658.286 us; speedup 1.0000x reference)
//
#include <hip/hip_runtime.h>
#include <math.h>

typedef __attribute__((ext_vector_type(8))) short short8;
typedef __attribute__((ext_vector_type(4))) float floatx4;
typedef unsigned short ushort_t;
typedef unsigned int uint_t;
typedef unsigned long long ull_t;

// Problem constants
constexpr int C_B   = 512;
constexpr int C_T   = 365;
constexpr int C_IN  = 10;
constexpr int C_H   = 256;
constexpr int C_OUT = 20;

// 16 strips x 5 roles = 80 blocks, 512 threads (8 waves) each.
// role 0 = X  : XG_k = x_k . Wih0^T (input-only, runs AHEAD, ring 4)
// role 1 = L0 : h0 chain, ENTIRELY BLOCK-LOCAL (LDS ping-pong, full-N GEMM)
// role 2,3 = A: G1_k = Wih1 . h0_k (consumes tagged h0, trails L0)
// role 4 = B  : h1 chain, BLOCK-LOCAL (Whh1 stream + LDS ping-pong) + G1
// Cross-block edges carry pipeline slack; serial chains never touch the fabric.
constexpr int NB = 80;

// Weight planes (ushort units): mat(3: Whh0,Wih1,Whh1) x (hi,lo) x [48nt][8ks][64][8]
constexpr size_t PLANE_U = 48ull * 8 * 64 * 8;   // 196608 ushorts
constexpr size_t US_H    = 6 * PLANE_U;          // ushort offset of ring region
// Ring layout in uint units from U0 = (uint*)(WS + US_H):
//   H0R: tagged ull, 3 planes x [512][256]  (uint span 786432)
//   XGR: f32, 4 planes x [512][768]
//   G1R: f32, 2 planes x [512][768]
//   H1F: packed uint [512][256]
//   SY : counters, per strip at +strip*64: cX+0 consL0+8 consA+16 cA+24 consB+32
constexpr size_t H0_E   = 512ull * 256;              // ull per h0 plane
constexpr size_t XG_U   = 786432;                    // uint idx
constexpr size_t XG_S   = 512ull * 768;              // uint per plane
constexpr size_t G1_U   = XG_U + 4 * XG_S;
constexpr size_t H1_U   = G1_U + 2 * XG_S;
constexpr size_t SY_U   = H1_U + 512ull * 256;
constexpr int SY_TOT = 2048;
constexpr unsigned SPIN_MAIN = 8192;                 // valve: visible, never hangs

__device__ __forceinline__ float fsig(float v)  { return 1.0f / (1.0f + __expf(-v)); }
__device__ __forceinline__ float ftanh(float v) { return 2.0f / (1.0f + __expf(-2.0f * v)) - 1.0f; }

__device__ __forceinline__ void split1(float x, ushort_t& hi, ushort_t& lo) {
    unsigned u = __float_as_uint(x);
    hi = (ushort_t)(u >> 16);
    float r = x - __uint_as_float(u & 0xffff0000u);
    lo = (ushort_t)(__float_as_uint(r) >> 16);
}
__device__ __forceinline__ uint_t packsplit(float x) {
    unsigned u = __float_as_uint(x);
    unsigned hib = u & 0xffff0000u;
    float r = x - __uint_as_float(hib);
    return hib | (__float_as_uint(r) >> 16);
}
__device__ __forceinline__ float lds_h(const ushort_t* hi, const ushort_t* lo, int idx) {
    return __uint_as_float(((unsigned)hi[idx]) << 16) + __uint_as_float(((unsigned)lo[idx]) << 16);
}

// AGENT-scope primitives (the proven cross-block mechanism)
__device__ __forceinline__ uint_t ald(const uint_t* p) {
    return __hip_atomic_load(p, __ATOMIC_RELAXED, __HIP_MEMORY_SCOPE_AGENT);
}
__device__ __forceinline__ void ast(uint_t* p, uint_t v) {
    __hip_atomic_store(p, v, __ATOMIC_RELAXED, __HIP_MEMORY_SCOPE_AGENT);
}
__device__ __forceinline__ ull_t ald8(const ull_t* p) {
    return __hip_atomic_load(p, __ATOMIC_RELAXED, __HIP_MEMORY_SCOPE_AGENT);
}
__device__ __forceinline__ void ast8(ull_t* p, ull_t v) {
    __hip_atomic_store(p, v, __ATOMIC_RELAXED, __HIP_MEMORY_SCOPE_AGENT);
}
__device__ __forceinline__ uint_t spin_ge(uint_t* p, uint_t tgt) {
    uint_t v = ald(p), it = 0;
    while (v < tgt) {
        if (++it > SPIN_MAIN) break;   // valve: wrong-but-terminating
        __builtin_amdgcn_s_sleep(2);
        v = ald(p);
    }
    return v;
}
__device__ __forceinline__ void bump(uint_t* p) {
    __hip_atomic_fetch_add(p, 1u, __ATOMIC_RELAXED, __HIP_MEMORY_SCOPE_AGENT);
}
// LDS-only barrier (no vmcnt drain: background sc1 stores keep flowing)
__device__ __forceinline__ void barrier_lds() {
    asm volatile("s_waitcnt lgkmcnt(0)\n\ts_barrier" ::: "memory");
}

__device__ __forceinline__ void commit4(uint_t u0, uint_t u1, uint_t u2, uint_t u3,
                                        ushort_t* s_hi, ushort_t* s_lo) {
    uint2 hv, lv;
    hv.x = (u0 >> 16) | (u1 & 0xffff0000u);
    hv.y = (u2 >> 16) | (u3 & 0xffff0000u);
    lv.x = (u0 & 0xffffu) | (u1 << 16);
    lv.y = (u2 & 0xffffu) | (u3 << 16);
    *(uint2*)s_hi = hv;
    *(uint2*)s_lo = lv;
}

// Poll+stage a [32][256] tagged plane into hi/lo LDS (512 threads, 16 ull each).
__device__ __forceinline__ void stage_tagged512(const ull_t* __restrict__ src, uint_t tag,
                                                ushort_t* s_hi, ushort_t* s_lo, int tid) {
    const int r0 = tid >> 4;            // 0..31
    const int c0 = (tid & 15) * 16;     // 16 ull per thread
    const ull_t* p = src + r0 * 256 + c0;
    ull_t v[16];
#pragma unroll
    for (int u = 0; u < 16; u++) v[u] = ald8(p + u);
    uint_t it = 0;
    for (;;) {
        uint_t bad = 0;
#pragma unroll
        for (int u = 0; u < 16; u++)
            bad |= ((uint_t)(v[u] >> 32) != tag) ? (1u << u) : 0u;
        if (!bad || it > SPIN_MAIN) break;   // valve
        ++it;
        __builtin_amdgcn_s_sleep(1);
#pragma unroll
        for (int u = 0; u < 16; u++)
            if (bad & (1u << u)) v[u] = ald8(p + u);
    }
#pragma unroll
    for (int u = 0; u < 16; u += 4) {
        const int so = r0 * 264 + c0 + u;
        commit4((uint_t)v[u], (uint_t)v[u+1], (uint_t)v[u+2], (uint_t)v[u+3],
                s_hi + so, s_lo + so);
    }
}

// ---------------- weight pre-pack (+ h0-tag/counter zeroing) ----------------
__global__ __launch_bounds__(256) void prep_pack(const float* __restrict__ Whh0,
                                                 const float* __restrict__ Wih1,
                                                 const float* __restrict__ Whh1,
                                                 ushort_t* __restrict__ PW) {
    const int blk = blockIdx.x;            // 144 = mat(3) x g(3) x jb(16)
    const int tid = threadIdx.x;

    // zero the 3 tagged h0 planes (tags >=1 are valid) + all counters
    ull_t* Z = (ull_t*)((uint_t*)(PW + US_H));
    for (size_t u = (size_t)blk * 256 + tid; u < 3 * H0_E; u += 144 * 256)
        ast8(Z + u, 0ull);
    if (blk == 0) {
        uint_t* SY = (uint_t*)(PW + US_H) + SY_U;
        for (int u = tid; u < SY_TOT; u += 256) ast(SY + u, 0u);
    }

    const int mat = blk / 48;
    const int rem = blk % 48;
    const int g   = rem / 16;
    const int jb  = rem % 16;
    const float* S = (mat == 0) ? Whh0 : (mat == 1) ? Wih1 : Whh1;

    const int jl  = tid >> 4;
    const int kc  = tid & 15;
    const int j   = jb * 16 + jl;
    const int nt  = jb * 3 + g;

    const float* src = S + (g * 256 + j) * 256 + kc * 16;
    float f[16];
#pragma unroll
    for (int q = 0; q < 4; q++) {
        float4 v = *(const float4*)(src + q * 4);
        f[q*4+0] = v.x; f[q*4+1] = v.y; f[q*4+2] = v.z; f[q*4+3] = v.w;
    }
    ushort_t hi[16], lo[16];
#pragma unroll
    for (int e = 0; e < 16; e++) split1(f[e], hi[e], lo[e]);

    ushort_t* dhi = PW + (size_t)(mat * 2 + 0) * PLANE_U;
    ushort_t* dlo = PW + (size_t)(mat * 2 + 1) * PLANE_U;
    const int ks = kc >> 1;
#pragma unroll
    for (int hh = 0; hh < 2; hh++) {
        const int quad = (kc & 1) * 2 + hh;
        const int L    = quad * 16 + jl;
        const size_t base = ((size_t)(nt * 8 + ks)) * 512 + L * 8;
        short8 vh, vl;
#pragma unroll
        for (int e = 0; e < 8; e++) { vh[e] = (short)hi[hh*8+e]; vl[e] = (short)lo[hh*8+e]; }
        *(short8*)(dhi + base) = vh;
        *(short8*)(dlo + base) = vl;
    }
}

// 2-jtile GEMM: A-frags from LDS (shared across jt), B streamed from L2.
// MFMA order per (ks,g): a0h*bh, a0l*bh, a0h*bl; then M-tile 1 — bit-exact
// vs the round-7 wave_gemm.
__device__ __forceinline__ void wave_gemm2(const ushort_t* sh_hi, const ushort_t* sh_lo,
                                           const ushort_t* __restrict__ WH,
                                           const ushort_t* __restrict__ WL,
                                           int jt0, int lane, floatx4 acc[2][3][2]) {
    const int m = lane & 15, quad = lane >> 4;
    const int aoff = m * 264 + quad * 8;
#pragma unroll
    for (int ks = 0; ks < 8; ks++) {
        short8 a0h = *(const short8*)(sh_hi + aoff + ks * 32);
        short8 a0l = *(const short8*)(sh_lo + aoff + ks * 32);
        short8 a1h = *(const short8*)(sh_hi + aoff + 16 * 264 + ks * 32);
        short8 a1l = *(const short8*)(sh_lo + aoff + 16 * 264 + ks * 32);
#pragma unroll
        for (int u = 0; u < 2; u++) {
#pragma unroll
            for (int g = 0; g < 3; g++) {
                const size_t boff = (size_t)(((jt0 + u) * 3 + g) * 8 + ks) * 512 + lane * 8;
                short8 bh = *(const short8*)(WH + boff);
                short8 bl = *(const short8*)(WL + boff);
                acc[u][g][0] = __builtin_amdgcn_mfma_f32_16x16x32_bf16(a0h, bh, acc[u][g][0], 0, 0, 0);
                acc[u][g][0] = __builtin_amdgcn_mfma_f32_16x16x32_bf16(a0l, bh, acc[u][g][0], 0, 0, 0);
                acc[u][g][0] = __builtin_amdgcn_mfma_f32_16x16x32_bf16(a0h, bl, acc[u][g][0], 0, 0, 0);
                acc[u][g][1] = __builtin_amdgcn_mfma_f32_16x16x32_bf16(a1h, bh, acc[u][g][1], 0, 0, 0);
                acc[u][g][1] = __builtin_amdgcn_mfma_f32_16x16x32_bf16(a1l, bh, acc[u][g][1], 0, 0, 0);
                acc[u][g][1] = __builtin_amdgcn_mfma_f32_16x16x32_bf16(a1h, bl, acc[u][g][1], 0, 0, 0);
            }
        }
    }
}

// 1-jtile variant (A blocks)
__device__ __forceinline__ void wave_gemm1(const ushort_t* sh_hi, const ushort_t* sh_lo,
                                           const ushort_t* __restrict__ WH,
                                           const ushort_t* __restrict__ WL,
                                           int jt, int lane, floatx4 acc[3][2]) {
    const int m = lane & 15, quad = lane >> 4;
    const int aoff = m * 264 + quad * 8;
#pragma unroll
    for (int ks = 0; ks < 8; ks++) {
        short8 a0h = *(const short8*)(sh_hi + aoff + ks * 32);
        short8 a0l = *(const short8*)(sh_lo + aoff + ks * 32);
        short8 a1h = *(const short8*)(sh_hi + aoff + 16 * 264 + ks * 32);
        short8 a1l = *(const short8*)(sh_lo + aoff + 16 * 264 + ks * 32);
#pragma unroll
        for (int g = 0; g < 3; g++) {
            const size_t boff = (size_t)((jt * 3 + g) * 8 + ks) * 512 + lane * 8;
            short8 bh = *(const short8*)(WH + boff);
            short8 bl = *(const short8*)(WL + boff);
            acc[g][0] = __builtin_amdgcn_mfma_f32_16x16x32_bf16(a0h, bh, acc[g][0], 0, 0, 0);
            acc[g][0] = __builtin_amdgcn_mfma_f32_16x16x32_bf16(a0l, bh, acc[g][0], 0, 0, 0);
            acc[g][0] = __builtin_amdgcn_mfma_f32_16x16x32_bf16(a0h, bl, acc[g][0], 0, 0, 0);
            acc[g][1] = __builtin_amdgcn_mfma_f32_16x16x32_bf16(a1h, bh, acc[g][1], 0, 0, 0);
            acc[g][1] = __builtin_amdgcn_mfma_f32_16x16x32_bf16(a1l, bh, acc[g][1], 0, 0, 0);
            acc[g][1] = __builtin_amdgcn_mfma_f32_16x16x32_bf16(a1h, bl, acc[g][1], 0, 0, 0);
        }
    }
}

__global__ __launch_bounds__(512) void gru_persistent(
    const float* __restrict__ x,
    const float* __restrict__ Wih0,
    const float* __restrict__ bih0, const float* __restrict__ bhh0,
    const float* __restrict__ bih1, const float* __restrict__ bhh1,
    ushort_t* __restrict__ WS)
{
    // SH[plane][hi/lo][32*264]: L0/B ping-pong state; A uses SH[0] for staging
    __shared__ __align__(16) ushort_t SH[2][2][32 * 264];
    __shared__ float wxl[768 * C_IN];    // X only (Wih0 rows)
    __shared__ float xs[32][C_IN];       // X only

    const int tid  = threadIdx.x;
    const int lane = tid & 63;
    const int w    = tid >> 6;          // wave 0..7
    const int jlo  = lane & 15;
    const int quad = lane >> 4;

    const int strip = blockIdx.x & 15;
    const int role  = blockIdx.x >> 4;   // 0=X 1=L0 2,3=A 4=B
    const int b0    = strip * 32;

    uint_t* const U0   = (uint_t*)(WS + US_H);
    ull_t*  const H0R  = (ull_t*)U0;
    uint_t* const XGR  = U0 + XG_U;
    uint_t* const G1R  = U0 + G1_U;
    uint_t* const H1F  = U0 + H1_U;
    uint_t* const SY   = U0 + SY_U + strip * 64;
    uint_t* const cX     = SY + 0;
    uint_t* const consL0 = SY + 8;
    uint_t* const consA  = SY + 16;
    uint_t* const cA     = SY + 24;
    uint_t* const consB  = SY + 32;

    if (role == 0) {
        // ==================== X: XG_j = x_j . Wih0^T (runs ahead) ====================
        for (int u = tid; u < 768 * C_IN; u += 512) wxl[u] = Wih0[u];
        const int rX = tid / C_IN, cXi = tid - rX * C_IN;   // tid < 320
        uint_t consc = 0;
#pragma unroll 1
        for (int j = 0; j < C_T; ++j) {
            float xv = 0.f;
            if (tid < 32 * C_IN) xv = x[(size_t)(b0 + rX) * (C_T * C_IN) + j * C_IN + cXi];
            if (tid < 32 * C_IN) xs[rX][cXi] = xv;
            barrier_lds();
            if (j >= 4) {                            // ring-4 WAR vs L0 consumption
                const uint_t need = (uint_t)(j - 3);
                if (consc < need) consc = spin_ge(consL0, need);
            }
            uint_t* const dst = XGR + (size_t)(j & 3) * XG_S + (size_t)b0 * 768;
#pragma unroll 1
            for (int u = tid; u < 32 * 768; u += 512) {
                const int row = u / 768, col = u - row * 768;
                const float* wr = &wxl[col * C_IN];
                float d = 0.f;
#pragma unroll
                for (int i = 0; i < C_IN; i++) d += xs[row][i] * wr[i];
                ast(dst + row * 768 + col, __float_as_uint(d));
            }
            __syncthreads();                          // drain XG stores
            if (tid == 0) bump(cX);
            barrier_lds();                            // xs reuse guard
        }
    } else if (role == 1) {
        // ==================== L0: block-local h0 chain ====================
        const int jt0 = 2 * w;
        int jj[2]; float b_r[2], b_z[2], b_in[2], b_hn[2];
#pragma unroll
        for (int u = 0; u < 2; u++) {
            const int j = (jt0 + u) * 16 + jlo;
            jj[u]   = j;
            b_r[u]  = bih0[j] + bhh0[j];
            b_z[u]  = bih0[256 + j] + bhh0[256 + j];
            b_in[u] = bih0[512 + j];
            b_hn[u] = bhh0[512 + j];
        }
        uint_t cXc = 0, consAc = 0;
#pragma unroll 1
        for (int k = 0; k < C_T; ++k) {
            // XG_k availability (X runs ahead; usually cached-satisfied)
            if (cXc < (uint_t)(k + 1)) cXc = spin_ge(cX, (uint_t)(k + 1));
            // prefetch XG into regs (latency hides under GEMM)
            float xg[2][3][2][4];
            const uint_t* xgp = XGR + (size_t)(k & 3) * XG_S;
#pragma unroll
            for (int u = 0; u < 2; u++)
#pragma unroll
                for (int g = 0; g < 3; g++)
#pragma unroll
                    for (int m = 0; m < 2; m++)
#pragma unroll
                        for (int r = 0; r < 4; r++) {
                            const int row = m * 16 + quad * 4 + r;
                            xg[u][g][m][r] = __uint_as_float(
                                ald(xgp + (size_t)(b0 + row) * 768 + g * 256 + jj[u]));
                        }

            floatx4 acc[2][3][2];
#pragma unroll
            for (int u = 0; u < 2; u++)
#pragma unroll
                for (int g = 0; g < 3; g++) { acc[u][g][0] = (floatx4){0,0,0,0}; acc[u][g][1] = (floatx4){0,0,0,0}; }
            if (k > 0)
                wave_gemm2(SH[(k - 1) & 1][0], SH[(k - 1) & 1][1],
                           WS, WS + PLANE_U, jt0, lane, acc);

            // h0 global ring-3 WAR: A's must have staged h0_{k-3}
            if (k >= 3) {
                const uint_t need = 2u * (uint_t)(k - 2);
                if (consAc < need) consAc = spin_ge(consA, need);
            }

            ull_t* const dst = H0R + (size_t)(k % 3) * H0_E;
            const ull_t tag = ((ull_t)(k + 1)) << 32;
            ushort_t* const nh = SH[k & 1][0];
            ushort_t* const nl = SH[k & 1][1];
            const ushort_t* const ph = SH[(k - 1) & 1][0];
            const ushort_t* const pl = SH[(k - 1) & 1][1];
#pragma unroll
            for (int u = 0; u < 2; u++) {
#pragma unroll
                for (int m = 0; m < 2; m++) {
#pragma unroll
                    for (int r = 0; r < 4; r++) {
                        const int row = m * 16 + quad * 4 + r;
                        const float hp = (k > 0) ? lds_h(ph, pl, row * 264 + jj[u]) : 0.f;
                        const float ar  = acc[u][0][m][r] + xg[u][0][m][r] + b_r[u];
                        const float az  = acc[u][1][m][r] + xg[u][1][m][r] + b_z[u];
                        const float inn = xg[u][2][m][r] + b_in[u];
                        const float hn  = acc[u][2][m][r] + b_hn[u];
                        const float rg = fsig(ar), zg = fsig(az);
                        const float nn = ftanh(inn + rg * hn);
                        const float hv = zg * (hp - nn) + nn;
                        ast8(dst + (size_t)(b0 + row) * 256 + jj[u], (ull_t)packsplit(hv) | tag);
                        ushort_t hh, hl; split1(hv, hh, hl);
                        nh[row * 264 + jj[u]] = hh;
                        nl[row * 264 + jj[u]] = hl;
                    }
                }
            }
            if (tid == 0) bump(consL0);   // fire-and-forget (gates X's ring only)
            barrier_lds();                // LDS plane k&1 complete; NO vm drain
        }
    } else if (role == 2 || role == 3) {
        // ==================== A: G1_k = Wih1 . h0_k ====================
        const int half = role - 2;
        const int jt = half * 8 + w;
        const int j  = jt * 16 + jlo;
        uint_t consBc = 0;
#pragma unroll 1
        for (int k = 0; k < C_T; ++k) {
            stage_tagged512(H0R + (size_t)(k % 3) * H0_E + (size_t)b0 * 256,
                            (uint_t)(k + 1), SH[0][0], SH[0][1], tid);
            barrier_lds();
            if (tid == 0) bump(consA);                 // h0_k staged
            if (k >= 2) {                              // G1 ring-2 WAR vs B
                const uint_t need = (uint_t)(k - 1);
                if (consBc < need) consBc = spin_ge(consB, need);
            }
            floatx4 acc[3][2];
#pragma unroll
            for (int g = 0; g < 3; g++) { acc[g][0] = (floatx4){0,0,0,0}; acc[g][1] = (floatx4){0,0,0,0}; }
            wave_gemm1(SH[0][0], SH[0][1], WS + 2 * PLANE_U, WS + 3 * PLANE_U, jt, lane, acc);

            uint_t* const g1 = G1R + (size_t)(k & 1) * XG_S + (size_t)b0 * 768;
#pragma unroll
            for (int g = 0; g < 3; g++)
#pragma unroll
                for (int m = 0; m < 2; m++)
#pragma unroll
                    for (int r = 0; r < 4; r++) {
                        const int row = m * 16 + quad * 4 + r;
                        ast(g1 + row * 768 + g * 256 + j, __float_as_uint(acc[g][m][r]));
                    }
            __syncthreads();                            // drain G1 stores + LDS reads done
            if (tid == 0) bump(cA);
        }
    } else {
        // ==================== B: block-local h1 chain + G1 combine ====================
        const int jt0 = 2 * w;
        int jj[2]; float cbr[2], cbz[2], cbi[2], cbh[2];
#pragma unroll
        for (int u = 0; u < 2; u++) {
            const int j = (jt0 + u) * 16 + jlo;
            jj[u]  = j;
            cbr[u] = bih1[j] + bhh1[j];
            cbz[u] = bih1[256 + j] + bhh1[256 + j];
            cbi[u] = bih1[512 + j];
            cbh[u] = bhh1[512 + j];
        }
        uint_t cAc = 0;
#pragma unroll 1
        for (int k = 0; k < C_T; ++k) {
            if (cAc < 2u * (uint_t)(k + 1)) cAc = spin_ge(cA, 2u * (uint_t)(k + 1));
            // prefetch G1_k into regs (latency hides under GEMM)
            float g1[2][3][2][4];
            const uint_t* gp = G1R + (size_t)(k & 1) * XG_S;
#pragma unroll
            for (int u = 0; u < 2; u++)
#pragma unroll
                for (int g = 0; g < 3; g++)
#pragma unroll
                    for (int m = 0; m < 2; m++)
#pragma unroll
                        for (int r = 0; r < 4; r++) {
                            const int row = m * 16 + quad * 4 + r;
                            g1[u][g][m][r] = __uint_as_float(
                                ald(gp + (size_t)(b0 + row) * 768 + g * 256 + jj[u]));
                        }

            floatx4 acc[2][3][2];
#pragma unroll
            for (int u = 0; u < 2; u++)
#pragma unroll
                for (int g = 0; g < 3; g++) { acc[u][g][0] = (floatx4){0,0,0,0}; acc[u][g][1] = (floatx4){0,0,0,0}; }
            if (k > 0)
                wave_gemm2(SH[(k - 1) & 1][0], SH[(k - 1) & 1][1],
                           WS + 4 * PLANE_U, WS + 5 * PLANE_U, jt0, lane, acc);

            ushort_t* const nh = SH[k & 1][0];
            ushort_t* const nl = SH[k & 1][1];
            const ushort_t* const ph = SH[(k - 1) & 1][0];
            const ushort_t* const pl = SH[(k - 1) & 1][1];
#pragma unroll
            for (int u = 0; u < 2; u++) {
#pragma unroll
                for (int m = 0; m < 2; m++) {
#pragma unroll
                    for (int r = 0; r < 4; r++) {
                        const int row = m * 16 + quad * 4 + r;
                        const float hp = (k > 0) ? lds_h(ph, pl, row * 264 + jj[u]) : 0.f;
                        const float ar  = g1[u][0][m][r] + acc[u][0][m][r] + cbr[u];
                        const float az  = g1[u][1][m][r] + acc[u][1][m][r] + cbz[u];
                        const float inn = g1[u][2][m][r] + cbi[u];
                        const float hn  = acc[u][2][m][r] + cbh[u];
                        const float rg = fsig(ar), zg = fsig(az);
                        const float nn = ftanh(inn + rg * hn);
                        const float hv = zg * (hp - nn) + nn;
                        ushort_t hh, hl; split1(hv, hh, hl);
                        nh[row * 264 + jj[u]] = hh;
                        nl[row * 264 + jj[u]] = hl;
                        if (k == C_T - 1)
                            ast(H1F + (size_t)(b0 + row) * 256 + jj[u], packsplit(hv));
                    }
                }
            }
            __syncthreads();                            // G1 consumed by all threads
            if (tid == 0) bump(consB);
        }
    }
}

__global__ __launch_bounds__(256) void classifier_kernel(
    const ushort_t* __restrict__ WS,
    const float* __restrict__ Wout, const float* __restrict__ bout,
    float* __restrict__ out)
{
    __shared__ float hs[32][C_H + 4];
    __shared__ float lg[32 * C_OUT];
    const int tid = threadIdx.x;
    const int b0  = blockIdx.x * 32;
    const uint_t* hp1 = (const uint_t*)(WS + US_H) + H1_U;
#pragma unroll
    for (int i = 0; i < 32; i++) {
        uint_t u = hp1[(b0 + i) * C_H + tid];
        hs[i][tid] = __uint_as_float(u & 0xffff0000u) + __uint_as_float(u << 16);
    }
    __syncthreads();
    for (int u = tid; u < 32 * C_OUT; u += 256) {
        int bb = u / C_OUT, o = u - bb * C_OUT;
        const float* wr = Wout + o * C_H;
        float acc = bout[o];
#pragma unroll 4
        for (int k = 0; k < C_H; k += 4) {
            float4 wv = *(const float4*)(wr + k);
            float4 hv = *(const float4*)(&hs[bb][k]);
            acc += wv.x*hv.x + wv.y*hv.y + wv.z*hv.z + wv.w*hv.w;
        }
        lg[u] = acc;
    }
    __syncthreads();
    if (tid < 32) {
        float mx = -1e30f;
#pragma unroll
        for (int o = 0; o < C_OUT; o++) mx = fmaxf(mx, lg[tid * C_OUT + o]);
        float e[C_OUT];
        float s = 0.0f;
#pragma unroll
        for (int o = 0; o < C_OUT; o++) { e[o] = __expf(lg[tid * C_OUT + o] - mx); s += e[o]; }
        float inv = 1.0f / s;
#pragma unroll
        for (int o = 0; o < C_OUT; o++) out[(b0 + tid) * C_OUT + o] = e[o] * inv;
    }
}

extern "C" void kernel_launch(void* const* d_in, const int* in_sizes, int n_in,
                              void* d_out, int out_size, void* d_ws, size_t ws_size,
                              hipStream_t stream) {
    const float* x    = (const float*)d_in[0];
    // d_in[1] = times (unused), d_in[2] = interpolation_method (unused)
    const float* Wih0 = (const float*)d_in[3];
    const float* Whh0 = (const float*)d_in[4];
    const float* bih0 = (const float*)d_in[5];
    const float* bhh0 = (const float*)d_in[6];
    const float* Wih1 = (const float*)d_in[7];
    const float* Whh1 = (const float*)d_in[8];
    const float* bih1 = (const float*)d_in[9];
    const float* bhh1 = (const float*)d_in[10];
    const float* Wout = (const float*)d_in[11];
    const float* bout = (const float*)d_in[12];
    float* out = (float*)d_out;
    ushort_t* WS = (ushort_t*)d_ws;

    // pack weights + zero h0 tags/counters (every launch, incl. graph replay)
    prep_pack<<<144, 256, 0, stream>>>(Whh0, Wih1, Whh1, WS);
    // whole recurrence in ONE dispatch; serial chains are block-local
    gru_persistent<<<NB, 512, 0, stream>>>(x, Wih0, bih0, bhh0, bih1, bhh1, WS);
    classifier_kernel<<<C_B / 32, 256, 0, stream>>>(WS, Wout, bout, out);
}